// Round 1
// baseline (12258.577 us; speedup 1.0000x reference)
//
#include <hip/hip_runtime.h>

#define BB 256
#define TT 512
#define HH 512

// v += shuffled(v) via DPP (VALU pipe, no LDS traffic)
template<int CTRL>
__device__ __forceinline__ float dpp_add(float v) {
    int s = __builtin_amdgcn_update_dpp(0, __builtin_bit_cast(int, v), CTRL, 0xf, 0xf, true);
    return v + __builtin_bit_cast(float, s);
}

// padded LDS float index for h element k:
// 16 rows (k>>5) with stride 9 chunks (36 floats, 144B) -> 16B-aligned b128 reads,
// bank-quad (row+chunk)%8 -> only 2-way aliasing across the 16 kb lanes (free).
__device__ __forceinline__ int h_slot(int k) {
    return ((k >> 5) * 36) + (((k >> 2) & 7) << 2) + (k & 3);
}

__global__ __launch_bounds__(1024) void rnn_irnn_kernel(
    const float* __restrict__ x,    // [B, T, 2]
    const float* __restrict__ Wh,   // [H, H] row-major, we need Wh[j,k]
    const float* __restrict__ Wx,   // [H, 2]
    float* __restrict__ out)        // [T+1, B, H]
{
    const int b   = blockIdx.x;     // one batch per workgroup (256 WGs = 256 CUs)
    const int tid = threadIdx.x;
    const int kb  = tid & 15;       // k-block 0..15 (32 k each) -- lane bits 0..3
    const int jb  = tid >> 4;       // j-block 0..63 (8 j each)

    __shared__ __align__(16) float hbuf[2][576];   // double-buffered padded h
    __shared__ __align__(16) float xs[TT * 2];     // x[b,:,:] stash (4 KB)

    // ---- setup ----
    xs[tid] = x[(size_t)b * (TT * 2) + tid];

    // Wh block -> 256 VGPRs (Wh stays register-resident for all 512 steps)
    float w[8][32];
    #pragma unroll
    for (int jj = 0; jj < 8; ++jj) {
        const float4* src = reinterpret_cast<const float4*>(Wh + (jb * 8 + jj) * HH + kb * 32);
        #pragma unroll
        for (int c = 0; c < 8; ++c) {
            float4 v = src[c];
            w[jj][c * 4 + 0] = v.x;
            w[jj][c * 4 + 1] = v.y;
            w[jj][c * 4 + 2] = v.z;
            w[jj][c * 4 + 3] = v.w;
        }
    }

    // writer lane (kb<8) owns output column jw = jb*8 + kb
    const int jw = jb * 8 + (kb & 7);
    const float wx0 = Wx[jw * 2 + 0];
    const float wx1 = Wx[jw * 2 + 1];

    // h0: [0..0,1,0..0] per batch; write LDS buffer 0 and out[0]
    if (tid < HH) {
        float h0 = (tid == 0) ? 1.0f : 0.0f;
        hbuf[0][h_slot(tid)] = h0;
        out[(size_t)b * HH + tid] = h0;
    }
    __syncthreads();

    const int wslot = h_slot(jw);
    float* optr = out + (size_t)BB * HH + (size_t)b * HH + jw;   // &out[1][b][jw]
    int cur = 0;

    for (int t = 0; t < TT; ++t) {
        // load this thread's 32 h values: 8x ds_read_b128, ~2-way bank alias (free)
        const float4* hv = reinterpret_cast<const float4*>(&hbuf[cur][0]) + kb * 9;
        float hk[32];
        #pragma unroll
        for (int r = 0; r < 8; ++r) {
            float4 v = hv[r];
            hk[r * 4 + 0] = v.x; hk[r * 4 + 1] = v.y;
            hk[r * 4 + 2] = v.z; hk[r * 4 + 3] = v.w;
        }

        // 256 fp32 FMAs: partial[jj] = sum_k Wh[j, k] * h[k] over this thread's k-slice
        float acc[8];
        #pragma unroll
        for (int jj = 0; jj < 8; ++jj) acc[jj] = w[jj][0] * hk[0];
        #pragma unroll
        for (int kk = 1; kk < 32; ++kk) {
            #pragma unroll
            for (int jj = 0; jj < 8; ++jj)
                acc[jj] = __builtin_fmaf(w[jj][kk], hk[kk], acc[jj]);
        }

        // butterfly reduce across the 16 kb-lanes (DPP row = 16 lanes):
        // XOR1, XOR2, then mirror ops (equivalent to XOR4/XOR8 once halves are uniform)
        #pragma unroll
        for (int jj = 0; jj < 8; ++jj) {
            float v = acc[jj];
            v = dpp_add<0xB1>(v);    // quad_perm [1,0,3,2]  : + lane^1
            v = dpp_add<0x4E>(v);    // quad_perm [2,3,0,1]  : + lane^2
            v = dpp_add<0x141>(v);   // row_half_mirror      : + other quad
            v = dpp_add<0x140>(v);   // row_mirror           : + other 8-group
            acc[jj] = v;
        }

        // lane kb (<8) picks acc[kb] -- loop-invariant compares hoist to SGPR masks
        float hsel = acc[0];
        #pragma unroll
        for (int i = 1; i < 8; ++i) hsel = (kb == i) ? acc[i] : hsel;

        float2 xv = *reinterpret_cast<const float2*>(xs + 2 * t);   // wave-uniform broadcast
        float hnew = fmaxf(__builtin_fmaf(xv.x, wx0, __builtin_fmaf(xv.y, wx1, hsel)), 0.0f);

        if (kb < 8) {
            hbuf[cur ^ 1][wslot] = hnew;   // next step's h
            *optr = hnew;                  // out[t+1][b][jw] -- contiguous 128B per wave
        }
        optr += BB * HH;
        cur ^= 1;
        __syncthreads();                   // one barrier per step
    }
}

extern "C" void kernel_launch(void* const* d_in, const int* in_sizes, int n_in,
                              void* d_out, int out_size, void* d_ws, size_t ws_size,
                              hipStream_t stream) {
    const float* x  = (const float*)d_in[0];
    const float* Wh = (const float*)d_in[1];
    const float* Wx = (const float*)d_in[2];
    float* out = (float*)d_out;
    rnn_irnn_kernel<<<BB, 1024, 0, stream>>>(x, Wh, Wx, out);
}